// Round 7
// baseline (350.980 us; speedup 1.0000x reference)
//
#include <hip/hip_runtime.h>

typedef unsigned short ushort_t;
typedef unsigned int uint_t;

typedef short bf16x8 __attribute__((ext_vector_type(8)));
typedef float f32x4 __attribute__((ext_vector_type(4)));

#define DIM 128
#define BSHIFT 8
#define BNODES 256           // nodes per bucket (1<<BSHIFT)
#define DBINS 64             // degree bins for balance-sort (Poisson(16): max deg ~45)
#define SEGCAP 8192          // LDS staging cap for a bucket's edge segment (avg 4096)

__device__ __forceinline__ ushort_t f2bf(float f) {
    uint_t x;
    __builtin_memcpy(&x, &f, 4);
    uint_t r = (x + 0x7fffu + ((x >> 16) & 1u)) >> 16;
    return (ushort_t)r;
}

// ---------- prep: x->bf16 cast + fragment-major weight buffers + bhist ----------
// fragbuf layout (per layer, 64 KB): frag f = nt*8+ks2 covers output cols
// [nt*16,nt*16+16) x K-chunk [ks2*32,ks2*32+32) of the concatenated K=256 GEMM
// (k2<128 -> W_l[k2][n], k2>=128 -> W_r[k2-128][n]). Within a frag, lane
// l=(quad,col) holds B[k=quad*8+j][n=col] at fragbuf[f*512 + l*8 + j] — so a
// wave's B-frag load is ONE fully-coalesced 1KB global_load_dwordx4 (L1-hot).
// NOTE (r5): do NOT replace these launches with a cooperative grid.sync
// mega-kernel — grid.sync+threadfence cost ~100us/phase at 391 blocks on
// 8-XCD MI355X; launches (~10us) are the cheap grid-wide barrier.

__global__ __launch_bounds__(256) void k_prep_bhist(
        const float* __restrict__ x, ushort_t* __restrict__ xb, int n4,
        const float* __restrict__ W1l, const float* __restrict__ W1r,
        const float* __restrict__ W2l, const float* __restrict__ W2r,
        ushort_t* __restrict__ fragbuf,
        const int* __restrict__ dst, int E, int NB, int* __restrict__ bucketCount,
        int prepBlocks) {
    if ((int)blockIdx.x >= prepBlocks) {
        __shared__ int hist[512];
        int blk = blockIdx.x - prepBlocks;   // 0..255
        int t = threadIdx.x;
        for (int b = t; b < NB; b += 256) hist[b] = 0;
        __syncthreads();
        int per = (E + 255) / 256;
        int beg = blk * per, end = min(beg + per, E);
        for (int i = beg + t; i < end; i += 256)
            atomicAdd(&hist[dst[i] >> BSHIFT], 1);
        __syncthreads();
        for (int b = t; b < NB; b += 256) {
            int v = hist[b];
            if (v) atomicAdd(&bucketCount[b], v);
        }
        return;
    }
    int i = blockIdx.x * 256 + threadIdx.x;
    if (i < n4) {
        float4 f = ((const float4*)x)[i];
        ushort4 u;
        u.x = f2bf(f.x); u.y = f2bf(f.y); u.z = f2bf(f.z); u.w = f2bf(f.w);
        ((ushort4*)xb)[i] = u;
    } else {
        int j = i - n4;                       // 0 .. 8191
        if (j < 2 * 64 * 64) {
            int layer = j >> 12;
            int rr = j & 4095;
            int f = rr >> 6, l = rr & 63;
            int nt = f >> 3, ks2 = f & 7;
            int col = l & 15, quad = l >> 4;
            int n = nt * 16 + col;
            int kb = ks2 * 32 + quad * 8;
            const float* Wl = layer ? W2l : W1l;
            const float* Wr = layer ? W2r : W1r;
            ushort_t* d = fragbuf + layer * 32768 + f * 512 + l * 8;
#pragma unroll
            for (int jj = 0; jj < 8; jj++) {
                int k2 = kb + jj;
                float v = (k2 < 128) ? Wl[k2 * DIM + n] : Wr[(k2 - 128) * DIM + n];
                d[jj] = f2bf(v);
            }
        }
    }
}

// ---------- CSR build via two-level bucket counting sort ----------
// k_bucketize does its own local scan of bucketCount; reservations via
// zero-initialized global cursors zcur. Block 0 publishes bucketBase.

__global__ __launch_bounds__(256) void k_bucketize(const int* __restrict__ src,
                                                   const int* __restrict__ dst, int E, int NB,
                                                   const int* __restrict__ bucketCount,
                                                   int* __restrict__ bucketBase_out,
                                                   int* __restrict__ row_ptr, int N,
                                                   int* __restrict__ zcur,
                                                   uint_t* __restrict__ bebuf) {
    __shared__ int bbase[512];
    __shared__ int hist[512];
    __shared__ int rbase[512];
    int t = threadIdx.x;
    int i0 = t, i1 = t + 256;
    int v0 = (i0 < NB) ? bucketCount[i0] : 0;
    int v1 = (i1 < NB) ? bucketCount[i1] : 0;
    bbase[i0] = v0; bbase[i1] = v1;
    __syncthreads();
    for (int off = 1; off < 512; off <<= 1) {
        int u0 = (i0 >= off) ? bbase[i0 - off] : 0;
        int u1 = (i1 >= off) ? bbase[i1 - off] : 0;
        __syncthreads();
        bbase[i0] += u0; bbase[i1] += u1;
        __syncthreads();
    }
    bbase[i0] -= v0;    // exclusive (own-slot update, later reads after barriers)
    bbase[i1] -= v1;
    if (blockIdx.x == 0) {
        if (i0 < NB) bucketBase_out[i0] = bbase[i0];
        if (i1 < NB) bucketBase_out[i1] = bbase[i1];
        if (t == 0) row_ptr[N] = E;
    }
    hist[i0] = 0; hist[i1] = 0;
    __syncthreads();
    int per = (E + gridDim.x - 1) / gridDim.x;
    int beg = blockIdx.x * per, end = min(beg + per, E);
    for (int i = beg + t; i < end; i += 256)
        atomicAdd(&hist[dst[i] >> BSHIFT], 1);
    __syncthreads();
    {
        int v = hist[i0];
        rbase[i0] = v ? (bbase[i0] + atomicAdd(&zcur[i0], v)) : 0;
        hist[i0] = 0;
        v = hist[i1];
        rbase[i1] = v ? (bbase[i1] + atomicAdd(&zcur[i1], v)) : 0;
        hist[i1] = 0;
    }
    __syncthreads();
    for (int i = beg + t; i < end; i += 256) {
        int d = dst[i], s = src[i];
        int b = d >> BSHIFT;
        int off = atomicAdd(&hist[b], 1);
        bebuf[rbase[b] + off] = ((uint_t)(d & (BNODES - 1)) << 24) | (uint_t)s;
    }
}

// k_bcsr: LDS-staged CSR build. The bucket's ~4096-edge segment is scattered
// into a 32KB LDS buffer via per-node cursors, each node's run is insertion-
// sorted ASCENDING BY SRC (thread t owns node t), then the whole segment is
// written out coalesced. The src-sort gives k_fused gather temporal locality:
// equal-degree waves in lockstep read edge j ~= src quantile j/deg, so the
// concurrent read set collapses to narrow bands of X instead of all 25.6MB.
// Also folds the degree histogram (hist[t] IS deg(node nodeBase+t)).
__global__ __launch_bounds__(256) void k_bcsr(const uint_t* __restrict__ bebuf,
                                              const int* __restrict__ bucketBase,
                                              const int* __restrict__ bucketCount, int N,
                                              int* __restrict__ row_ptr, int* __restrict__ csr,
                                              int* __restrict__ dhist) {
    __shared__ int hist[BNODES];
    __shared__ int cur[BNODES];
    __shared__ int dh[DBINS];
    __shared__ int seg[SEGCAP];
    int t = threadIdx.x;
    int b = blockIdx.x;
    int ebase = bucketBase[b], cnt = bucketCount[b];
    int nodeBase = b << BSHIFT;
    hist[t] = 0;
    if (t < DBINS) dh[t] = 0;
    __syncthreads();
    for (int i = t; i < cnt; i += 256)
        atomicAdd(&hist[bebuf[ebase + i] >> 24], 1);
    __syncthreads();
    int v = hist[t];                         // degree of node nodeBase+t
    int node = nodeBase + t;
    if (node < N) atomicAdd(&dh[min(v, DBINS - 1)], 1);
    for (int off = 1; off < 256; off <<= 1) {
        int u = (t >= off) ? hist[t - off] : 0;
        __syncthreads();
        hist[t] += u;
        __syncthreads();
    }
    int excl = hist[t] - v;
    if (node < N) row_ptr[node] = ebase + excl;
    cur[t] = excl;
    __syncthreads();
    if (cnt <= SEGCAP) {
        for (int i = t; i < cnt; i += 256) {
            uint_t e = bebuf[ebase + i];
            int dl = (int)(e >> 24);
            int pos = atomicAdd(&cur[dl], 1);
            seg[pos] = (int)(e & 0xFFFFFFu);
        }
        __syncthreads();
        // per-node ascending-src insertion sort (d avg 16, max ~50)
        for (int i = 1; i < v; i++) {
            int key = seg[excl + i];
            int j = i - 1;
            while (j >= 0 && seg[excl + j] > key) {
                seg[excl + j + 1] = seg[excl + j];
                j--;
            }
            seg[excl + j + 1] = key;
        }
        __syncthreads();
        for (int i = t; i < cnt; i += 256)
            csr[ebase + i] = seg[i];         // coalesced write-out
    } else {
        // fallback (never hit for Poisson(4096) buckets): direct scatter, unsorted
        for (int i = t; i < cnt; i += 256) {
            uint_t e = bebuf[ebase + i];
            int dl = (int)(e >> 24);
            int pos = atomicAdd(&cur[dl], 1);
            csr[ebase + pos] = (int)(e & 0xFFFFFFu);
        }
    }
    __syncthreads();
    if (t < DBINS) {
        int c = dh[t];
        if (c) atomicAdd(&dhist[t], c);
    }
}

// ---------- degree-balance permutation (local scan of dhist) ----------

__global__ __launch_bounds__(256) void k_dperm(const int* __restrict__ rp, int N,
                                               const int* __restrict__ dhist,
                                               int* __restrict__ zdcur, int* __restrict__ perm) {
    __shared__ int eb[DBINS];
    __shared__ int h[DBINS];
    __shared__ int rb[DBINS];
    int t = threadIdx.x;
    int v = (t < DBINS) ? dhist[t] : 0;
    if (t < DBINS) { eb[t] = v; h[t] = 0; }
    __syncthreads();
    for (int off = 1; off < DBINS; off <<= 1) {
        int u = (t < DBINS && t >= off) ? eb[t - off] : 0;
        __syncthreads();
        if (t < DBINS) eb[t] += u;
        __syncthreads();
    }
    if (t < DBINS) eb[t] -= v;   // exclusive base (own-slot)
    int i = blockIdx.x * 256 + t;
    int b = -1;
    if (i < N) {
        int d = rp[i + 1] - rp[i];
        b = min(d, DBINS - 1);
        atomicAdd(&h[b], 1);
    }
    __syncthreads();
    if (t < DBINS) {
        int hv = h[t];
        rb[t] = hv ? (eb[t] + atomicAdd(&zdcur[t], hv)) : 0;
        h[t] = 0;
    }
    __syncthreads();
    if (i < N) {
        int off = atomicAdd(&h[b], 1);
        perm[rb[b] + off] = i;
    }
}

// ---------- fused aggregate + SAGE GEMM ----------
// Block = 4 waves = 16 perm-consecutive (equal-degree) nodes.
// Phase 1: 16 lanes/node gather+mean (src-ascending edge lists -> concurrent
//   blocks read the same src quantile bands -> L2 temporal locality), packed
//   bf16 into an 8KB LDS tile [16 rows][256 dims] = [agg | self], 16B chunks
//   XOR-swizzled by (row&7).
// Phase 2: wave w computes output cols [w*32,..+32): A-frags from LDS,
//   B-frags coalesced from fragbuf (L1-hot), 16 MFMAs, bias(+ReLU).
// Epilogue (bf16 out): restage through LDS then full-row 256B stores.

__device__ __forceinline__ void acc8(float* a, uint4 p) {
    union { uint_t u; float f; } c;
    c.u = p.x << 16;         a[0] += c.f;
    c.u = p.x & 0xffff0000u; a[1] += c.f;
    c.u = p.y << 16;         a[2] += c.f;
    c.u = p.y & 0xffff0000u; a[3] += c.f;
    c.u = p.z << 16;         a[4] += c.f;
    c.u = p.z & 0xffff0000u; a[5] += c.f;
    c.u = p.w << 16;         a[6] += c.f;
    c.u = p.w & 0xffff0000u; a[7] += c.f;
}

template <bool RELU, bool OUT_BF16>
__global__ __launch_bounds__(256) void k_fused(const ushort_t* __restrict__ X,
                                               const int* __restrict__ row_ptr,
                                               const int* __restrict__ csr,
                                               const int* __restrict__ perm,
                                               const ushort_t* __restrict__ fragbuf,
                                               const float* __restrict__ bias,
                                               void* __restrict__ Out, int N) {
    __shared__ __align__(16) ushort_t tile[16 * 256];   // 8 KB
    __shared__ int nd[16];
    int t = threadIdx.x;
    int gl = t >> 4;                 // node slot 0..15
    int sl = t & 15;                 // 16B slice of the row
    int gidx = blockIdx.x * 16 + gl;
    bool act = (gidx < N);
    int node = 0, beg = 0, end = 0;
    if (act) {
        node = perm[gidx];
        beg = row_ptr[node];
        end = row_ptr[node + 1];
    }
    if (sl == 0) nd[gl] = node;

    // ---- gather (x4 unroll, proven k_agg form) ----
    float a[8] = {0.f, 0.f, 0.f, 0.f, 0.f, 0.f, 0.f, 0.f};
    int e = beg;
    for (; e + 4 <= end; e += 4) {
        int s0 = csr[e + 0], s1 = csr[e + 1], s2 = csr[e + 2], s3 = csr[e + 3];
        uint4 p0 = *(const uint4*)(X + (size_t)s0 * DIM + sl * 8);
        uint4 p1 = *(const uint4*)(X + (size_t)s1 * DIM + sl * 8);
        uint4 p2 = *(const uint4*)(X + (size_t)s2 * DIM + sl * 8);
        uint4 p3 = *(const uint4*)(X + (size_t)s3 * DIM + sl * 8);
        acc8(a, p0); acc8(a, p1); acc8(a, p2); acc8(a, p3);
    }
    for (; e < end; e++) {
        int s = csr[e];
        uint4 p = *(const uint4*)(X + (size_t)s * DIM + sl * 8);
        acc8(a, p);
    }
    int cnt = end - beg;
    float scl = (cnt > 0) ? 1.f / (float)cnt : 0.f;

    int swz = gl & 7;
    uint4 o;
    o.x = (uint_t)f2bf(a[0] * scl) | ((uint_t)f2bf(a[1] * scl) << 16);
    o.y = (uint_t)f2bf(a[2] * scl) | ((uint_t)f2bf(a[3] * scl) << 16);
    o.z = (uint_t)f2bf(a[4] * scl) | ((uint_t)f2bf(a[5] * scl) << 16);
    o.w = (uint_t)f2bf(a[6] * scl) | ((uint_t)f2bf(a[7] * scl) << 16);
    *(uint4*)(tile + gl * 256 + ((sl ^ swz) * 8)) = o;           // agg dims
    uint4 p;
    if (act) p = *(const uint4*)(X + (size_t)node * DIM + sl * 8);
    else     p = (uint4){0u, 0u, 0u, 0u};
    *(uint4*)(tile + gl * 256 + (((16 + sl) ^ swz) * 8)) = p;    // self dims
    __syncthreads();

    // ---- MFMA phase ----
    int lane = t & 63, w = t >> 6;
    int m = lane & 15, quad = lane >> 4;
    bf16x8 af[8];
#pragma unroll
    for (int ks2 = 0; ks2 < 8; ks2++) {
        int c = (ks2 * 4 + quad) ^ (m & 7);
        af[ks2] = *(const bf16x8*)(tile + m * 256 + c * 8);
    }
    f32x4 acc0 = (f32x4){0.f, 0.f, 0.f, 0.f};
    f32x4 acc1 = (f32x4){0.f, 0.f, 0.f, 0.f};
    const ushort_t* fb0 = fragbuf + (size_t)((w * 2 + 0) * 8) * 512 + lane * 8;
    const ushort_t* fb1 = fragbuf + (size_t)((w * 2 + 1) * 8) * 512 + lane * 8;
#pragma unroll
    for (int ks2 = 0; ks2 < 8; ks2++) {
        bf16x8 b0 = *(const bf16x8*)(fb0 + ks2 * 512);
        acc0 = __builtin_amdgcn_mfma_f32_16x16x32_bf16(af[ks2], b0, acc0, 0, 0, 0);
    }
#pragma unroll
    for (int ks2 = 0; ks2 < 8; ks2++) {
        bf16x8 b1 = *(const bf16x8*)(fb1 + ks2 * 512);
        acc1 = __builtin_amdgcn_mfma_f32_16x16x32_bf16(af[ks2], b1, acc1, 0, 0, 0);
    }
    int c0 = (w * 2 + 0) * 16 + m;
    int c1 = (w * 2 + 1) * 16 + m;
    float bv0 = bias[c0], bv1 = bias[c1];

    if (OUT_BF16) {
        float r0v[4], r1v[4];
#pragma unroll
        for (int r = 0; r < 4; r++) {
            float v0 = acc0[r] + bv0, v1 = acc1[r] + bv1;
            if (RELU) { v0 = fmaxf(v0, 0.f); v1 = fmaxf(v1, 0.f); }
            r0v[r] = v0; r1v[r] = v1;
        }
        __syncthreads();                     // all af reads complete; tile free
        ushort_t* to = tile;                 // reuse as [16][128]
#pragma unroll
        for (int r = 0; r < 4; r++) {
            int mrow = quad * 4 + r;
            to[mrow * 128 + c0] = f2bf(r0v[r]);
            to[mrow * 128 + c1] = f2bf(r1v[r]);
        }
        __syncthreads();
        int gl2 = t >> 4, sl2 = t & 15;
        int g2 = blockIdx.x * 16 + gl2;
        if (g2 < N) {
            uint4 vv = *(const uint4*)(to + gl2 * 128 + sl2 * 8);
            *(uint4*)((ushort_t*)Out + (size_t)nd[gl2] * DIM + sl2 * 8) = vv;
        }
    } else {
#pragma unroll
        for (int r = 0; r < 4; r++) {
            int mrow = quad * 4 + r;
            int gI = blockIdx.x * 16 + mrow;
            if (gI < N) {
                int nodeW = nd[mrow];
                float v0 = acc0[r] + bv0;
                float v1 = acc1[r] + bv1;
                if (RELU) { v0 = fmaxf(v0, 0.f); v1 = fmaxf(v1, 0.f); }
                ((float*)Out)[(size_t)nodeW * DIM + c0] = v0;
                ((float*)Out)[(size_t)nodeW * DIM + c1] = v1;
            }
        }
    }
}

// ---------- host ----------

extern "C" void kernel_launch(void* const* d_in, const int* in_sizes, int n_in,
                              void* d_out, int out_size, void* d_ws, size_t ws_size,
                              hipStream_t stream) {
    const int N = in_sizes[0] / DIM;   // 100000
    const int E = in_sizes[1] / 2;     // 1600000
    const int NB = (N + BNODES - 1) >> BSHIFT;   // 391 buckets

    const float* x   = (const float*)d_in[0];
    const int*   ei  = (const int*)d_in[1];
    const int*   src = ei;
    const int*   dst = ei + E;
    const float* W1l = (const float*)d_in[2];
    const float* b1  = (const float*)d_in[3];
    const float* W1r = (const float*)d_in[4];
    const float* W2l = (const float*)d_in[5];
    const float* b2  = (const float*)d_in[6];
    const float* W2r = (const float*)d_in[7];
    float* out = (float*)d_out;

    char* ws = (char*)d_ws;
    size_t off = 0;
    auto alloc = [&](size_t bytes) -> char* {
        char* p = ws + off;
        off = (off + bytes + 255) & ~(size_t)255;
        return p;
    };

    // zero-init span: bucketCount, dhist, zcur, zdcur (contiguous allocs)
    int*      bucketCount  = (int*)alloc((size_t)NB * 4);
    int*      dhist        = (int*)alloc((size_t)DBINS * 4);
    int*      zcur         = (int*)alloc((size_t)NB * 4);
    int*      zdcur        = (int*)alloc((size_t)DBINS * 4);
    size_t    zspan        = (size_t)((char*)zdcur + DBINS * 4 - (char*)bucketCount);
    int*      bucketBase   = (int*)alloc((size_t)NB * 4);
    int*      row_ptr      = (int*)alloc((size_t)(N + 1) * 4);
    int*      csr          = (int*)alloc((size_t)E * 4);
    uint_t*   bebuf        = (uint_t*)alloc((size_t)E * 4);
    ushort_t* xb           = (ushort_t*)alloc((size_t)N * DIM * 2);
    ushort_t* hb           = (ushort_t*)alloc((size_t)N * DIM * 2);
    ushort_t* fragbuf      = (ushort_t*)alloc((size_t)2 * 32768 * 2);   // 2 layers x 64 KB
    int*      perm         = (int*)bebuf;   // bebuf dead after k_bcsr; reuse as perm

    hipMemsetAsync(bucketCount, 0, zspan, stream);

    // x->bf16 + fragment-major weights + bucket histogram, single launch
    {
        int n4 = N * DIM / 4;
        int total = n4 + 2 * 64 * 64;
        int prepBlocks = (total + 255) / 256;
        k_prep_bhist<<<dim3(prepBlocks + 256), dim3(256), 0, stream>>>(
            x, xb, n4, W1l, W1r, W2l, W2r, fragbuf,
            dst, E, NB, bucketCount, prepBlocks);
    }
    // CSR build (bucketize self-scans; bcsr stages in LDS + src-sorts + folds dhist)
    k_bucketize<<<dim3(256), dim3(256), 0, stream>>>(src, dst, E, NB, bucketCount,
                                                     bucketBase, row_ptr, N, zcur, bebuf);
    k_bcsr<<<dim3(NB), dim3(256), 0, stream>>>(bebuf, bucketBase, bucketCount, N,
                                               row_ptr, csr, dhist);
    // degree-balance permutation (self-scans dhist; perm aliases bebuf)
    const int nblk = (N + 255) / 256;
    k_dperm<<<dim3(nblk), dim3(256), 0, stream>>>(row_ptr, N, dhist, zdcur, perm);

    const int ntiles = (N + 15) / 16;    // 6250 blocks
    k_fused<true, true><<<dim3(ntiles), dim3(256), 0, stream>>>(
        xb, row_ptr, csr, perm, fragbuf, b1, hb, N);
    k_fused<false, false><<<dim3(ntiles), dim3(256), 0, stream>>>(
        hb, row_ptr, csr, perm, fragbuf + 32768, b2, out, N);

    (void)n_in; (void)out_size; (void)ws_size;
}

// Round 8
// 309.750 us; speedup vs baseline: 1.1331x; 1.1331x over previous
//
#include <hip/hip_runtime.h>

typedef unsigned short ushort_t;
typedef unsigned int uint_t;

typedef short bf16x8 __attribute__((ext_vector_type(8)));
typedef float f32x4 __attribute__((ext_vector_type(4)));

#define DIM 128
#define BSHIFT 8
#define BNODES 256           // nodes per bucket (1<<BSHIFT)

__device__ __forceinline__ ushort_t f2bf(float f) {
    uint_t x;
    __builtin_memcpy(&x, &f, 4);
    uint_t r = (x + 0x7fffu + ((x >> 16) & 1u)) >> 16;
    return (ushort_t)r;
}

// ---------- prep: x->bf16 cast + fragment-major weight buffers + bhist ----------
// fragbuf layout (per layer, 64 KB): frag f = nt*8+ks2 covers output cols
// [nt*16,nt*16+16) x K-chunk [ks2*32,ks2*32+32) of the concatenated K=256 GEMM
// (k2<128 -> W_l[k2][n], k2>=128 -> W_r[k2-128][n]). Within a frag, lane
// l=(quad,col) holds B[k=quad*8+j][n=col] at fragbuf[f*512 + l*8 + j] — so a
// wave's B-frag load is ONE fully-coalesced 1KB global_load_dwordx4 (L1-hot).
// NOTE (r5): do NOT replace these launches with a cooperative grid.sync
// mega-kernel — grid.sync+threadfence cost ~100us/phase at 391 blocks on
// 8-XCD MI355X; launches (~10us) are the cheap grid-wide barrier.
// NOTE (r7): do NOT src-sort edge lists in k_bcsr — per-node insertion sort
// cost +31us and gather locality gain was ~1% (order-statistic band >> L2).

__global__ __launch_bounds__(256) void k_prep_bhist(
        const float* __restrict__ x, ushort_t* __restrict__ xb, int n4,
        const float* __restrict__ W1l, const float* __restrict__ W1r,
        const float* __restrict__ W2l, const float* __restrict__ W2r,
        ushort_t* __restrict__ fragbuf,
        const int* __restrict__ dst, int E, int NB, int* __restrict__ bucketCount,
        int prepBlocks) {
    if ((int)blockIdx.x >= prepBlocks) {
        __shared__ int hist[512];
        int blk = blockIdx.x - prepBlocks;   // 0..255
        int t = threadIdx.x;
        for (int b = t; b < NB; b += 256) hist[b] = 0;
        __syncthreads();
        int per = (E + 255) / 256;
        int beg = blk * per, end = min(beg + per, E);
        for (int i = beg + t; i < end; i += 256)
            atomicAdd(&hist[dst[i] >> BSHIFT], 1);
        __syncthreads();
        for (int b = t; b < NB; b += 256) {
            int v = hist[b];
            if (v) atomicAdd(&bucketCount[b], v);
        }
        return;
    }
    int i = blockIdx.x * 256 + threadIdx.x;
    if (i < n4) {
        float4 f = ((const float4*)x)[i];
        ushort4 u;
        u.x = f2bf(f.x); u.y = f2bf(f.y); u.z = f2bf(f.z); u.w = f2bf(f.w);
        ((ushort4*)xb)[i] = u;
    } else {
        int j = i - n4;                       // 0 .. 8191
        if (j < 2 * 64 * 64) {
            int layer = j >> 12;
            int rr = j & 4095;
            int f = rr >> 6, l = rr & 63;
            int nt = f >> 3, ks2 = f & 7;
            int col = l & 15, quad = l >> 4;
            int n = nt * 16 + col;
            int kb = ks2 * 32 + quad * 8;
            const float* Wl = layer ? W2l : W1l;
            const float* Wr = layer ? W2r : W1r;
            ushort_t* d = fragbuf + layer * 32768 + f * 512 + l * 8;
#pragma unroll
            for (int jj = 0; jj < 8; jj++) {
                int k2 = kb + jj;
                float v = (k2 < 128) ? Wl[k2 * DIM + n] : Wr[(k2 - 128) * DIM + n];
                d[jj] = f2bf(v);
            }
        }
    }
}

// ---------- CSR build via two-level bucket counting sort ----------
// k_bucketize does its own local scan of bucketCount; reservations via
// zero-initialized global cursors zcur. Block 0 publishes bucketBase.

__global__ __launch_bounds__(256) void k_bucketize(const int* __restrict__ src,
                                                   const int* __restrict__ dst, int E, int NB,
                                                   const int* __restrict__ bucketCount,
                                                   int* __restrict__ bucketBase_out,
                                                   int* __restrict__ row_ptr, int N,
                                                   int* __restrict__ zcur,
                                                   uint_t* __restrict__ bebuf) {
    __shared__ int bbase[512];
    __shared__ int hist[512];
    __shared__ int rbase[512];
    int t = threadIdx.x;
    int i0 = t, i1 = t + 256;
    int v0 = (i0 < NB) ? bucketCount[i0] : 0;
    int v1 = (i1 < NB) ? bucketCount[i1] : 0;
    bbase[i0] = v0; bbase[i1] = v1;
    __syncthreads();
    for (int off = 1; off < 512; off <<= 1) {
        int u0 = (i0 >= off) ? bbase[i0 - off] : 0;
        int u1 = (i1 >= off) ? bbase[i1 - off] : 0;
        __syncthreads();
        bbase[i0] += u0; bbase[i1] += u1;
        __syncthreads();
    }
    bbase[i0] -= v0;    // exclusive (own-slot update, later reads after barriers)
    bbase[i1] -= v1;
    if (blockIdx.x == 0) {
        if (i0 < NB) bucketBase_out[i0] = bbase[i0];
        if (i1 < NB) bucketBase_out[i1] = bbase[i1];
        if (t == 0) row_ptr[N] = E;
    }
    hist[i0] = 0; hist[i1] = 0;
    __syncthreads();
    int per = (E + gridDim.x - 1) / gridDim.x;
    int beg = blockIdx.x * per, end = min(beg + per, E);
    for (int i = beg + t; i < end; i += 256)
        atomicAdd(&hist[dst[i] >> BSHIFT], 1);
    __syncthreads();
    {
        int v = hist[i0];
        rbase[i0] = v ? (bbase[i0] + atomicAdd(&zcur[i0], v)) : 0;
        hist[i0] = 0;
        v = hist[i1];
        rbase[i1] = v ? (bbase[i1] + atomicAdd(&zcur[i1], v)) : 0;
        hist[i1] = 0;
    }
    __syncthreads();
    for (int i = beg + t; i < end; i += 256) {
        int d = dst[i], s = src[i];
        int b = d >> BSHIFT;
        int off = atomicAdd(&hist[b], 1);
        bebuf[rbase[b] + off] = ((uint_t)(d & (BNODES - 1)) << 24) | (uint_t)s;
    }
}

// k_bcsr: per-bucket CSR finalize (r6-proven form; no sort, no dhist).
__global__ __launch_bounds__(256) void k_bcsr(const uint_t* __restrict__ bebuf,
                                              const int* __restrict__ bucketBase,
                                              const int* __restrict__ bucketCount, int N,
                                              int* __restrict__ row_ptr, int* __restrict__ csr) {
    __shared__ int hist[BNODES];
    __shared__ int cur[BNODES];
    int t = threadIdx.x;
    int b = blockIdx.x;
    int ebase = bucketBase[b], cnt = bucketCount[b];
    int nodeBase = b << BSHIFT;
    hist[t] = 0;
    __syncthreads();
    for (int i = t; i < cnt; i += 256)
        atomicAdd(&hist[bebuf[ebase + i] >> 24], 1);
    __syncthreads();
    int v = hist[t];
    int node = nodeBase + t;
    for (int off = 1; off < 256; off <<= 1) {
        int u = (t >= off) ? hist[t - off] : 0;
        __syncthreads();
        hist[t] += u;
        __syncthreads();
    }
    int excl = hist[t] - v;
    if (node < N) row_ptr[node] = ebase + excl;
    cur[t] = excl;
    __syncthreads();
    for (int i = t; i < cnt; i += 256) {
        uint_t e = bebuf[ebase + i];
        int dl = (int)(e >> 24);
        int pos = atomicAdd(&cur[dl], 1);
        csr[ebase + pos] = (int)(e & 0xFFFFFFu);
    }
}

// ---------- fused aggregate + SAGE GEMM ----------
// Block = 4 waves = 16 consecutive nodes (direct indexing; degree-balance
// perm dropped in r8 — r0-vs-r3 evidence showed it ~null while costing a
// launch: imbalance wastes issue slots, and the gather is memory-system
// bound at VALUBusy 27%, not issue bound).
// Phase 1: 16 lanes/node gather+mean, packed bf16 into an 8KB LDS tile
//   [16 rows][256 dims] = [agg | self] (concatenated K=256 vs [W_l ; W_r]),
//   16B chunks XOR-swizzled by (row&7).
// Phase 2: wave w computes output cols [w*32,..+32): A-frags from LDS,
//   B-frags coalesced from fragbuf (L1-hot), 16 MFMAs, bias(+ReLU).
// Epilogue (bf16 out): restage through LDS then full-row 256B stores.

__device__ __forceinline__ void acc8(float* a, uint4 p) {
    union { uint_t u; float f; } c;
    c.u = p.x << 16;         a[0] += c.f;
    c.u = p.x & 0xffff0000u; a[1] += c.f;
    c.u = p.y << 16;         a[2] += c.f;
    c.u = p.y & 0xffff0000u; a[3] += c.f;
    c.u = p.z << 16;         a[4] += c.f;
    c.u = p.z & 0xffff0000u; a[5] += c.f;
    c.u = p.w << 16;         a[6] += c.f;
    c.u = p.w & 0xffff0000u; a[7] += c.f;
}

template <bool RELU, bool OUT_BF16>
__global__ __launch_bounds__(256) void k_fused(const ushort_t* __restrict__ X,
                                               const int* __restrict__ row_ptr,
                                               const int* __restrict__ csr,
                                               const ushort_t* __restrict__ fragbuf,
                                               const float* __restrict__ bias,
                                               void* __restrict__ Out, int N) {
    __shared__ __align__(16) ushort_t tile[16 * 256];   // 8 KB
    int t = threadIdx.x;
    int gl = t >> 4;                 // node slot 0..15
    int sl = t & 15;                 // 16B slice of the row
    int node = blockIdx.x * 16 + gl; // direct node indexing
    bool act = (node < N);
    int beg = 0, end = 0;
    if (act) {
        beg = row_ptr[node];
        end = row_ptr[node + 1];
    }

    // ---- gather (x4 unroll, proven k_agg form) ----
    float a[8] = {0.f, 0.f, 0.f, 0.f, 0.f, 0.f, 0.f, 0.f};
    int e = beg;
    for (; e + 4 <= end; e += 4) {
        int s0 = csr[e + 0], s1 = csr[e + 1], s2 = csr[e + 2], s3 = csr[e + 3];
        uint4 p0 = *(const uint4*)(X + (size_t)s0 * DIM + sl * 8);
        uint4 p1 = *(const uint4*)(X + (size_t)s1 * DIM + sl * 8);
        uint4 p2 = *(const uint4*)(X + (size_t)s2 * DIM + sl * 8);
        uint4 p3 = *(const uint4*)(X + (size_t)s3 * DIM + sl * 8);
        acc8(a, p0); acc8(a, p1); acc8(a, p2); acc8(a, p3);
    }
    for (; e < end; e++) {
        int s = csr[e];
        uint4 p = *(const uint4*)(X + (size_t)s * DIM + sl * 8);
        acc8(a, p);
    }
    int cnt = end - beg;
    float scl = (cnt > 0) ? 1.f / (float)cnt : 0.f;

    int swz = gl & 7;
    uint4 o;
    o.x = (uint_t)f2bf(a[0] * scl) | ((uint_t)f2bf(a[1] * scl) << 16);
    o.y = (uint_t)f2bf(a[2] * scl) | ((uint_t)f2bf(a[3] * scl) << 16);
    o.z = (uint_t)f2bf(a[4] * scl) | ((uint_t)f2bf(a[5] * scl) << 16);
    o.w = (uint_t)f2bf(a[6] * scl) | ((uint_t)f2bf(a[7] * scl) << 16);
    *(uint4*)(tile + gl * 256 + ((sl ^ swz) * 8)) = o;           // agg dims
    uint4 p;
    if (act) p = *(const uint4*)(X + (size_t)node * DIM + sl * 8);
    else     p = (uint4){0u, 0u, 0u, 0u};
    *(uint4*)(tile + gl * 256 + (((16 + sl) ^ swz) * 8)) = p;    // self dims
    __syncthreads();

    // ---- MFMA phase ----
    int lane = t & 63, w = t >> 6;
    int m = lane & 15, quad = lane >> 4;
    bf16x8 af[8];
#pragma unroll
    for (int ks2 = 0; ks2 < 8; ks2++) {
        int c = (ks2 * 4 + quad) ^ (m & 7);
        af[ks2] = *(const bf16x8*)(tile + m * 256 + c * 8);
    }
    f32x4 acc0 = (f32x4){0.f, 0.f, 0.f, 0.f};
    f32x4 acc1 = (f32x4){0.f, 0.f, 0.f, 0.f};
    const ushort_t* fb0 = fragbuf + (size_t)((w * 2 + 0) * 8) * 512 + lane * 8;
    const ushort_t* fb1 = fragbuf + (size_t)((w * 2 + 1) * 8) * 512 + lane * 8;
#pragma unroll
    for (int ks2 = 0; ks2 < 8; ks2++) {
        bf16x8 b0 = *(const bf16x8*)(fb0 + ks2 * 512);
        acc0 = __builtin_amdgcn_mfma_f32_16x16x32_bf16(af[ks2], b0, acc0, 0, 0, 0);
    }
#pragma unroll
    for (int ks2 = 0; ks2 < 8; ks2++) {
        bf16x8 b1 = *(const bf16x8*)(fb1 + ks2 * 512);
        acc1 = __builtin_amdgcn_mfma_f32_16x16x32_bf16(af[ks2], b1, acc1, 0, 0, 0);
    }
    int c0 = (w * 2 + 0) * 16 + m;
    int c1 = (w * 2 + 1) * 16 + m;
    float bv0 = bias[c0], bv1 = bias[c1];

    if (OUT_BF16) {
        float r0v[4], r1v[4];
#pragma unroll
        for (int r = 0; r < 4; r++) {
            float v0 = acc0[r] + bv0, v1 = acc1[r] + bv1;
            if (RELU) { v0 = fmaxf(v0, 0.f); v1 = fmaxf(v1, 0.f); }
            r0v[r] = v0; r1v[r] = v1;
        }
        __syncthreads();                     // all af reads complete; tile free
        ushort_t* to = tile;                 // reuse as [16][128]
#pragma unroll
        for (int r = 0; r < 4; r++) {
            int mrow = quad * 4 + r;
            to[mrow * 128 + c0] = f2bf(r0v[r]);
            to[mrow * 128 + c1] = f2bf(r1v[r]);
        }
        __syncthreads();
        int gl2 = t >> 4, sl2 = t & 15;
        int n2 = blockIdx.x * 16 + gl2;
        if (n2 < N) {
            uint4 vv = *(const uint4*)(to + gl2 * 128 + sl2 * 8);
            *(uint4*)((ushort_t*)Out + (size_t)n2 * DIM + sl2 * 8) = vv;
        }
    } else {
#pragma unroll
        for (int r = 0; r < 4; r++) {
            int mrow = quad * 4 + r;
            int nodeW = blockIdx.x * 16 + mrow;
            if (nodeW < N) {
                float v0 = acc0[r] + bv0;
                float v1 = acc1[r] + bv1;
                if (RELU) { v0 = fmaxf(v0, 0.f); v1 = fmaxf(v1, 0.f); }
                ((float*)Out)[(size_t)nodeW * DIM + c0] = v0;
                ((float*)Out)[(size_t)nodeW * DIM + c1] = v1;
            }
        }
    }
}

// ---------- host ----------

extern "C" void kernel_launch(void* const* d_in, const int* in_sizes, int n_in,
                              void* d_out, int out_size, void* d_ws, size_t ws_size,
                              hipStream_t stream) {
    const int N = in_sizes[0] / DIM;   // 100000
    const int E = in_sizes[1] / 2;     // 1600000
    const int NB = (N + BNODES - 1) >> BSHIFT;   // 391 buckets

    const float* x   = (const float*)d_in[0];
    const int*   ei  = (const int*)d_in[1];
    const int*   src = ei;
    const int*   dst = ei + E;
    const float* W1l = (const float*)d_in[2];
    const float* b1  = (const float*)d_in[3];
    const float* W1r = (const float*)d_in[4];
    const float* W2l = (const float*)d_in[5];
    const float* b2  = (const float*)d_in[6];
    const float* W2r = (const float*)d_in[7];
    float* out = (float*)d_out;

    char* ws = (char*)d_ws;
    size_t off = 0;
    auto alloc = [&](size_t bytes) -> char* {
        char* p = ws + off;
        off = (off + bytes + 255) & ~(size_t)255;
        return p;
    };

    // zero-init span: bucketCount + zcur (contiguous allocs)
    int*      bucketCount  = (int*)alloc((size_t)NB * 4);
    int*      zcur         = (int*)alloc((size_t)NB * 4);
    size_t    zspan        = (size_t)((char*)zcur + NB * 4 - (char*)bucketCount);
    int*      bucketBase   = (int*)alloc((size_t)NB * 4);
    int*      row_ptr      = (int*)alloc((size_t)(N + 1) * 4);
    int*      csr          = (int*)alloc((size_t)E * 4);
    uint_t*   bebuf        = (uint_t*)alloc((size_t)E * 4);
    ushort_t* xb           = (ushort_t*)alloc((size_t)N * DIM * 2);
    ushort_t* hb           = (ushort_t*)alloc((size_t)N * DIM * 2);
    ushort_t* fragbuf      = (ushort_t*)alloc((size_t)2 * 32768 * 2);   // 2 layers x 64 KB

    hipMemsetAsync(bucketCount, 0, zspan, stream);

    // x->bf16 + fragment-major weights + bucket histogram, single launch
    {
        int n4 = N * DIM / 4;
        int total = n4 + 2 * 64 * 64;
        int prepBlocks = (total + 255) / 256;
        k_prep_bhist<<<dim3(prepBlocks + 256), dim3(256), 0, stream>>>(
            x, xb, n4, W1l, W1r, W2l, W2r, fragbuf,
            dst, E, NB, bucketCount, prepBlocks);
    }
    // CSR build (bucketize self-scans; bcsr finalizes per bucket)
    k_bucketize<<<dim3(256), dim3(256), 0, stream>>>(src, dst, E, NB, bucketCount,
                                                     bucketBase, row_ptr, N, zcur, bebuf);
    k_bcsr<<<dim3(NB), dim3(256), 0, stream>>>(bebuf, bucketBase, bucketCount, N,
                                               row_ptr, csr);

    const int ntiles = (N + 15) / 16;    // 6250 blocks
    k_fused<true, true><<<dim3(ntiles), dim3(256), 0, stream>>>(
        xb, row_ptr, csr, fragbuf, b1, hb, N);
    k_fused<false, false><<<dim3(ntiles), dim3(256), 0, stream>>>(
        hb, row_ptr, csr, fragbuf + 32768, b2, out, N);

    (void)n_in; (void)out_size; (void)ws_size;
}